// Round 2
// baseline (940.474 us; speedup 1.0000x reference)
//
#include <hip/hip_runtime.h>

typedef __attribute__((ext_vector_type(4))) float f32x4;
typedef __attribute__((ext_vector_type(8))) __bf16 bf16x8;
typedef __attribute__((ext_vector_type(8))) unsigned short us8;
typedef unsigned short u16;

#define SSILU_SCALE (1.0f / 0.6f)
#define INV_SQRT2 0.70710678118654752f

__device__ __forceinline__ u16 f2bf(float f) {
    __bf16 h = (__bf16)f;   // HW RNE convert (v_cvt_pk_bf16_f32 class)
    return __builtin_bit_cast(u16, h);
}
__device__ __forceinline__ float bf2f(u16 h) {
    union { unsigned int u; float f; } v; v.u = ((unsigned int)h) << 16;
    return v.f;
}
__device__ __forceinline__ float ssilu(float x) {
    return x / (1.0f + __expf(-x)) * SSILU_SCALE;
}

// ---------------------------------------------------------------------------
// prep: transpose-convert weights fp32 -> bf16 Wt[N][K]; zero d_out.
// ---------------------------------------------------------------------------
__global__ __launch_bounds__(256) void prep_kernel(
    const float* __restrict__ Win, const float* __restrict__ W1a,
    const float* __restrict__ W1b, const float* __restrict__ W2a,
    const float* __restrict__ W2b, u16* __restrict__ WtIn,
    u16* __restrict__ WtR, float* __restrict__ out, int outN) {
    int i = blockIdx.x * 256 + threadIdx.x;
    if (i < 256 * 1280) {
        int n = i / 1280, k = i % 1280;
        WtIn[i] = f2bf(Win[k * 256 + n]);
        return;
    }
    int j = i - 256 * 1280;
    if (j < 4 * 65536) {
        int m = j >> 16, r = j & 65535;
        int n = r >> 8, k = r & 255;
        const float* W = (m == 0) ? W1a : (m == 1) ? W1b : (m == 2) ? W2a : W2b;
        WtR[j] = f2bf(W[k * 256 + n]);
        return;
    }
    int z = j - 4 * 65536;
    if (z < outN) out[z] = 0.0f;
}

// ---------------------------------------------------------------------------
// 64x256 tile GEMM on a resident LDS x-tile; B-fragments straight from L2.
// AB: swizzled [64][256] bf16 LDS tile (512B rows). Wg: bf16 [256][256] Wt.
// ---------------------------------------------------------------------------
__device__ __forceinline__ void gemm_lds(const char* AB, const u16* __restrict__ Wg,
                                         int w, int lo, int hi, f32x4 acc[4][4]) {
#pragma unroll
    for (int m = 0; m < 4; m++)
#pragma unroll
        for (int n = 0; n < 4; n++) acc[m][n] = (f32x4){0.f, 0.f, 0.f, 0.f};
#pragma unroll
    for (int kk = 0; kk < 8; ++kk) {
        int kbyte = kk * 64 + hi * 16;
        bf16x8 af[4], bv[4];
#pragma unroll
        for (int m = 0; m < 4; m++) {
            int r = m * 16 + lo;
            af[m] = __builtin_bit_cast(bf16x8,
                *(const us8*)(AB + r * 512 + (kbyte ^ ((r & 7) << 4))));
        }
#pragma unroll
        for (int n = 0; n < 4; n++) {
            int cc = w * 64 + n * 16 + lo;
            bv[n] = __builtin_bit_cast(bf16x8,
                *(const us8*)(Wg + (size_t)cc * 256 + kk * 32 + hi * 8));
        }
#pragma unroll
        for (int m = 0; m < 4; m++)
#pragma unroll
            for (int n = 0; n < 4; n++)
                acc[m][n] = __builtin_amdgcn_mfma_f32_16x16x32_bf16(
                    af[m], bv[n], acc[m][n], 0, 0, 0);
    }
}

// ---------------------------------------------------------------------------
// fused: h = ssilu(x_cat @ W_in); 2 residual blocks; W_out dot; scatter-add.
// Block: 64 edge-rows, 4 waves (wave w -> output cols 64w..64w+63).
// Phase 1: A fp32->bf16 reg-staged into 2x8KB dbuf (aliased into tb),
//          one barrier per K-step, W_in fragments read from L2.
// Phase 2: previous resid body on the resident xb tile.
// ---------------------------------------------------------------------------
__global__ __launch_bounds__(256) void fused_kernel(
    const float* __restrict__ A, const u16* __restrict__ WtIn,
    const u16* __restrict__ WtR, const float* __restrict__ Wout,
    const float* __restrict__ evec, const int* __restrict__ eidx,
    float* __restrict__ out) {
    __shared__ u16 xb[64 * 256];   // [row][col] swizzled, 512B rows
    __shared__ u16 tb[64 * 256];   // temp; first 16KB doubles as A-staging dbuf
    __shared__ float fpart[4][64];
    const int t = threadIdx.x, w = t >> 6, l = t & 63;
    const int lo = l & 15, hi = l >> 4;
    const long rowbase = (long)blockIdx.x * 64;
    char* xbB = (char*)xb;
    char* tbB = (char*)tb;
    char* As0 = (char*)tb;          // 8 KB, swizzled [64][64] bf16 (128B rows)
    char* As1 = (char*)tb + 8192;   // 8 KB

    f32x4 acc[4][4];
#pragma unroll
    for (int m = 0; m < 4; m++)
#pragma unroll
        for (int n = 0; n < 4; n++) acc[m][n] = (f32x4){0.f, 0.f, 0.f, 0.f};

    // ---------------- phase 1: x = ssilu(x_cat @ W_in) ----------------
    float4 va[2][2];
    auto LOADA = [&](int kb) {
#pragma unroll
        for (int c = 0; c < 2; ++c) {
            int idx = t + c * 256;
            int r = idx >> 3, k8 = (idx & 7) * 8;
            const float* s = A + (rowbase + r) * 1280 + kb + k8;
            va[c][0] = *(const float4*)s;
            va[c][1] = *(const float4*)(s + 4);
        }
    };
    auto WRITEA = [&](char* dst) {
#pragma unroll
        for (int c = 0; c < 2; ++c) {
            int idx = t + c * 256;
            int r = idx >> 3, k8 = (idx & 7) * 8;
            us8 p;
            p[0] = f2bf(va[c][0].x); p[1] = f2bf(va[c][0].y);
            p[2] = f2bf(va[c][0].z); p[3] = f2bf(va[c][0].w);
            p[4] = f2bf(va[c][1].x); p[5] = f2bf(va[c][1].y);
            p[6] = f2bf(va[c][1].z); p[7] = f2bf(va[c][1].w);
            *(us8*)(dst + r * 128 + ((k8 * 2) ^ ((r & 7) << 4))) = p;
        }
    };

    LOADA(0);
    WRITEA(As0);
    __syncthreads();
    for (int kt = 0; kt < 20; ++kt) {
        if (kt + 1 < 20) LOADA((kt + 1) * 64);          // issue next-tile loads early
        const char* AB = (kt & 1) ? As1 : As0;
#pragma unroll
        for (int kk = 0; kk < 2; ++kk) {
            int kbyte = kk * 64 + hi * 16;
            bf16x8 af[4], bv[4];
#pragma unroll
            for (int m = 0; m < 4; m++) {
                int r = m * 16 + lo;
                af[m] = __builtin_bit_cast(bf16x8,
                    *(const us8*)(AB + r * 128 + (kbyte ^ ((r & 7) << 4))));
            }
#pragma unroll
            for (int n = 0; n < 4; n++) {
                int cc = w * 64 + n * 16 + lo;
                bv[n] = __builtin_bit_cast(bf16x8,
                    *(const us8*)(WtIn + (size_t)cc * 1280 + kt * 64 + kk * 32 + hi * 8));
            }
#pragma unroll
            for (int m = 0; m < 4; m++)
#pragma unroll
                for (int n = 0; n < 4; n++)
                    acc[m][n] = __builtin_amdgcn_mfma_f32_16x16x32_bf16(
                        af[m], bv[n], acc[m][n], 0, 0, 0);
        }
        if (kt + 1 < 20) WRITEA((kt & 1) ? As0 : As1);  // other buffer: safe, one barrier/iter
        __syncthreads();
    }
    // epilogue: x -> xb (swizzled bf16)
#pragma unroll
    for (int m = 0; m < 4; m++)
#pragma unroll
        for (int n = 0; n < 4; n++)
#pragma unroll
            for (int j = 0; j < 4; j++) {
                int r = m * 16 + hi * 4 + j;
                int cc = w * 64 + n * 16 + lo;
                *(u16*)(xbB + r * 512 + ((cc * 2) ^ ((r & 7) << 4))) =
                    f2bf(ssilu(acc[m][n][j]));
            }
    __syncthreads();

    // ---------------- phase 2: residual stack ----------------
    // G1: t1 = ssilu(x @ W1a) -> tb
    gemm_lds(xbB, WtR + 0 * 65536, w, lo, hi, acc);
#pragma unroll
    for (int m = 0; m < 4; m++)
#pragma unroll
        for (int n = 0; n < 4; n++)
#pragma unroll
            for (int j = 0; j < 4; j++) {
                int r = m * 16 + hi * 4 + j;
                int cc = w * 64 + n * 16 + lo;
                *(u16*)(tbB + r * 512 + ((cc * 2) ^ ((r & 7) << 4))) =
                    f2bf(ssilu(acc[m][n][j]));
            }
    __syncthreads();

    // G2: x = (x + ssilu(t1 @ W1b)) * INV_SQRT2 -> xb
    gemm_lds(tbB, WtR + 1 * 65536, w, lo, hi, acc);
#pragma unroll
    for (int m = 0; m < 4; m++)
#pragma unroll
        for (int n = 0; n < 4; n++)
#pragma unroll
            for (int j = 0; j < 4; j++) {
                int r = m * 16 + hi * 4 + j;
                int cc = w * 64 + n * 16 + lo;
                char* p = xbB + r * 512 + ((cc * 2) ^ ((r & 7) << 4));
                float xn = (bf2f(*(u16*)p) + ssilu(acc[m][n][j])) * INV_SQRT2;
                *(u16*)p = f2bf(xn);
            }
    __syncthreads();

    // G3: t1 = ssilu(x @ W2a) -> tb
    gemm_lds(xbB, WtR + 2 * 65536, w, lo, hi, acc);
#pragma unroll
    for (int m = 0; m < 4; m++)
#pragma unroll
        for (int n = 0; n < 4; n++)
#pragma unroll
            for (int j = 0; j < 4; j++) {
                int r = m * 16 + hi * 4 + j;
                int cc = w * 64 + n * 16 + lo;
                *(u16*)(tbB + r * 512 + ((cc * 2) ^ ((r & 7) << 4))) =
                    f2bf(ssilu(acc[m][n][j]));
            }
    __syncthreads();

    // G4: x_final = (x + ssilu(t1 @ W2b)) * INV_SQRT2, fp32 in regs
    gemm_lds(tbB, WtR + 3 * 65536, w, lo, hi, acc);
    float wo[4];
#pragma unroll
    for (int n = 0; n < 4; n++) wo[n] = Wout[w * 64 + n * 16 + lo];

    float part[4][4];
#pragma unroll
    for (int m = 0; m < 4; m++)
#pragma unroll
        for (int j = 0; j < 4; j++) part[m][j] = 0.f;
#pragma unroll
    for (int m = 0; m < 4; m++)
#pragma unroll
        for (int n = 0; n < 4; n++)
#pragma unroll
            for (int j = 0; j < 4; j++) {
                int r = m * 16 + hi * 4 + j;
                int cc = w * 64 + n * 16 + lo;
                const char* p = xbB + r * 512 + ((cc * 2) ^ ((r & 7) << 4));
                float xf = (bf2f(*(const u16*)p) + ssilu(acc[m][n][j])) * INV_SQRT2;
                part[m][j] += xf * wo[n];
            }
#pragma unroll
    for (int m = 0; m < 4; m++)
#pragma unroll
        for (int j = 0; j < 4; j++) {
            float v = part[m][j];
            v += __shfl_xor(v, 1);
            v += __shfl_xor(v, 2);
            v += __shfl_xor(v, 4);
            v += __shfl_xor(v, 8);
            if (lo == 0) fpart[w][m * 16 + hi * 4 + j] = v;
        }
    __syncthreads();

    if (t < 64) {
        int r = t;
        float F = fpart[0][r] + fpart[1][r] + fpart[2][r] + fpart[3][r];
        long e = rowbase + r;
        float vx = evec[e * 3 + 0], vy = evec[e * 3 + 1], vz = evec[e * 3 + 2];
        int a = eidx[e];
        atomicAdd(&out[a * 3 + 0], F * vx);
        atomicAdd(&out[a * 3 + 1], F * vy);
        atomicAdd(&out[a * 3 + 2], F * vz);
    }
}

extern "C" void kernel_launch(void* const* d_in, const int* in_sizes, int n_in,
                              void* d_out, int out_size, void* d_ws, size_t ws_size,
                              hipStream_t stream) {
    const float* x_cat = (const float*)d_in[0];
    const float* evec  = (const float*)d_in[1];
    const int*   eidx  = (const int*)d_in[2];
    const float* Win   = (const float*)d_in[3];
    const float* W1a   = (const float*)d_in[4];
    const float* W1b   = (const float*)d_in[5];
    const float* W2a   = (const float*)d_in[6];
    const float* W2b   = (const float*)d_in[7];
    const float* Wout  = (const float*)d_in[8];
    float* out = (float*)d_out;
    const int E = in_sizes[1] / 3;  // 200000

    u16* WtIn = (u16*)d_ws;
    u16* WtR  = WtIn + 256 * 1280;

    int prepN = 256 * 1280 + 4 * 65536 + out_size;
    prep_kernel<<<(prepN + 255) / 256, 256, 0, stream>>>(
        Win, W1a, W1b, W2a, W2b, WtIn, WtR, out, out_size);
    fused_kernel<<<E / 64, 256, 0, stream>>>(
        x_cat, WtIn, WtR, Wout, evec, eidx, out);
}

// Round 3
// 623.014 us; speedup vs baseline: 1.5096x; 1.5096x over previous
//
#include <hip/hip_runtime.h>

typedef __attribute__((ext_vector_type(4))) float f32x4;
typedef __attribute__((ext_vector_type(8))) __bf16 bf16x8;
typedef __attribute__((ext_vector_type(8))) unsigned short us8;
typedef unsigned short u16;

#define SSILU_SCALE (1.0f / 0.6f)
#define INV_SQRT2 0.70710678118654752f

__device__ __forceinline__ u16 f2bf(float f) {
    __bf16 h = (__bf16)f;
    return __builtin_bit_cast(u16, h);
}
__device__ __forceinline__ float bf2f(u16 h) {
    union { unsigned int u; float f; } v; v.u = ((unsigned int)h) << 16;
    return v.f;
}
__device__ __forceinline__ float ssilu(float x) {
    return x / (1.0f + __expf(-x)) * SSILU_SCALE;
}
// async global->LDS copy, 16B per lane; lds must be wave-uniform base (+lane*16 in HW)
__device__ __forceinline__ void async16(void* lds, const void* g) {
    __builtin_amdgcn_global_load_lds(
        (const __attribute__((address_space(1))) unsigned int*)g,
        (__attribute__((address_space(3))) unsigned int*)lds, 16, 0, 0);
}

// ---------------------------------------------------------------------------
// prep:
//  WtInT: W_in^T as 20 K-tiles, each the exact 32KB swizzled-LDS image
//         (byte off within tile = col*128 + ((k*2) ^ ((col&7)<<4)))
//  Wfrag: 4 matrices as [g][w][kk][n][lane][8] bf16 -> 1KB coalesced wave chunks
//  out:   zeroed
// ---------------------------------------------------------------------------
__global__ __launch_bounds__(256) void prep_kernel(
    const float* __restrict__ Win, const float* __restrict__ W1a,
    const float* __restrict__ W1b, const float* __restrict__ W2a,
    const float* __restrict__ W2b, u16* __restrict__ WtInT,
    u16* __restrict__ Wfrag, float* __restrict__ out, int outN) {
    int i = blockIdx.x * 256 + threadIdx.x;
    if (i < 327680) {                    // 20 tiles x 256 cols x 64 k
        int kt = i >> 14, r = i & 16383;
        int col = r >> 6, k = r & 63;
        int off = col * 128 + ((k * 2) ^ ((col & 7) << 4));
        WtInT[kt * 16384 + (off >> 1)] = f2bf(Win[(kt * 64 + k) * 256 + col]);
        return;
    }
    int j = i - 327680;
    if (j < 262144) {                    // 4 x 65536
        int g = j >> 16, r = j & 65535;
        int chunk = r >> 9, within = r & 511;
        int lane = within >> 3, e = within & 7;
        int w = chunk >> 5, kk = (chunk >> 2) & 7, n = chunk & 3;
        int lo = lane & 15, hi = lane >> 4;
        int col = w * 64 + n * 16 + lo;
        int k = kk * 32 + hi * 8 + e;
        const float* W = (g == 0) ? W1a : (g == 1) ? W1b : (g == 2) ? W2a : W2b;
        Wfrag[j] = f2bf(W[k * 256 + col]);
        return;
    }
    int z = j - 262144;
    if (z < outN) out[z] = 0.0f;
}

// ---------------------------------------------------------------------------
// gemm1: H_img = ssilu(x_cat @ W_in), 64 rows x 256 cols per block.
// A reg-staged fp32->bf16 into swizzled LDS; B async global_load_lds of the
// pre-swizzled tile image. H written as pre-swizzled 32KB block images.
// ---------------------------------------------------------------------------
__global__ __launch_bounds__(256, 3) void gemm1_kernel(
    const float* __restrict__ A, const u16* __restrict__ WtInT,
    u16* __restrict__ H) {
    __shared__ u16 Bs[256 * 64];   // 32KB: swizzled B tile (and epilogue bounce)
    __shared__ u16 As[64 * 64];    // 8KB: swizzled A tile (128B rows)
    const int t = threadIdx.x, w = t >> 6, l = t & 63;
    const int lo = l & 15, hi = l >> 4;
    const long rowbase = (long)blockIdx.x * 64;
    char* AsB = (char*)As;
    char* BsB = (char*)Bs;

    f32x4 acc[4][4];
#pragma unroll
    for (int m = 0; m < 4; m++)
#pragma unroll
        for (int n = 0; n < 4; n++) acc[m][n] = (f32x4){0.f, 0.f, 0.f, 0.f};

    float4 va[2][2];
    auto LOADA = [&](int kb) {
#pragma unroll
        for (int c = 0; c < 2; ++c) {
            int idx = t + c * 256;
            int r = idx >> 3, k8 = (idx & 7) * 8;
            const float* s = A + (rowbase + r) * 1280 + kb + k8;
            va[c][0] = *(const float4*)s;
            va[c][1] = *(const float4*)(s + 4);
        }
    };
    auto WRITEA = [&]() {
#pragma unroll
        for (int c = 0; c < 2; ++c) {
            int idx = t + c * 256;
            int r = idx >> 3, k8 = (idx & 7) * 8;
            us8 p;
            p[0] = f2bf(va[c][0].x); p[1] = f2bf(va[c][0].y);
            p[2] = f2bf(va[c][0].z); p[3] = f2bf(va[c][0].w);
            p[4] = f2bf(va[c][1].x); p[5] = f2bf(va[c][1].y);
            p[6] = f2bf(va[c][1].z); p[7] = f2bf(va[c][1].w);
            *(us8*)(AsB + r * 128 + ((k8 * 2) ^ ((r & 7) << 4))) = p;
        }
    };

    LOADA(0);
    for (int kt = 0; kt < 20; ++kt) {
        __syncthreads();                 // all waves done reading As/Bs
        WRITEA();                        // A(kt) regs -> LDS
        {
            const char* gsrc = (const char*)WtInT + (size_t)kt * 32768 +
                               w * 1024 + l * 16;
            char* ldst = BsB + w * 1024;
#pragma unroll
            for (int c = 0; c < 8; ++c)
                async16(ldst + c * 4096, gsrc + c * 4096);
        }
        __syncthreads();                 // vmcnt+lgkm drain: A,B ready
        if (kt + 1 < 20) LOADA((kt + 1) * 64);   // overlap next loads with MFMA
#pragma unroll
        for (int kk = 0; kk < 2; ++kk) {
            int kbyte = kk * 64 + hi * 16;
            bf16x8 af[4], bv[4];
#pragma unroll
            for (int m = 0; m < 4; m++) {
                int r = m * 16 + lo;
                af[m] = __builtin_bit_cast(bf16x8,
                    *(const us8*)(AsB + r * 128 + (kbyte ^ ((r & 7) << 4))));
            }
#pragma unroll
            for (int n = 0; n < 4; n++) {
                int cc = w * 64 + n * 16 + lo;
                bv[n] = __builtin_bit_cast(bf16x8,
                    *(const us8*)(BsB + cc * 128 + (kbyte ^ ((cc & 7) << 4))));
            }
#pragma unroll
            for (int m = 0; m < 4; m++)
#pragma unroll
                for (int n = 0; n < 4; n++)
                    acc[m][n] = __builtin_amdgcn_mfma_f32_16x16x32_bf16(
                        af[m], bv[n], acc[m][n], 0, 0, 0);
        }
    }
    __syncthreads();
    // epilogue: build swizzled H image in Bs, then coalesced 32KB store
#pragma unroll
    for (int m = 0; m < 4; m++)
#pragma unroll
        for (int n = 0; n < 4; n++)
#pragma unroll
            for (int j = 0; j < 4; j++) {
                int r = m * 16 + hi * 4 + j;
                int cc = w * 64 + n * 16 + lo;
                *(u16*)(BsB + r * 512 + ((cc * 2) ^ ((r & 7) << 4))) =
                    f2bf(ssilu(acc[m][n][j]));
            }
    __syncthreads();
    char* dst = (char*)H + (size_t)blockIdx.x * 32768;
#pragma unroll
    for (int c = 0; c < 8; ++c) {
        int off = (t + c * 256) * 16;
        *(us8*)(dst + off) = *(const us8*)(BsB + off);
    }
}

// ---------------------------------------------------------------------------
// resid: 2 residual blocks + W_out dot + scatter-add on resident 64x256 tile.
// W fragments stream coalesced from Wfrag (L2-hot, 1KB wave chunks).
// ---------------------------------------------------------------------------
__device__ __forceinline__ void gemm_lds(const char* AB, const u16* __restrict__ Wfw,
                                         int l, int lo, int hi, f32x4 acc[4][4]) {
#pragma unroll
    for (int m = 0; m < 4; m++)
#pragma unroll
        for (int n = 0; n < 4; n++) acc[m][n] = (f32x4){0.f, 0.f, 0.f, 0.f};
#pragma unroll
    for (int kk = 0; kk < 8; ++kk) {
        int kbyte = kk * 64 + hi * 16;
        bf16x8 af[4], bv[4];
#pragma unroll
        for (int n = 0; n < 4; n++)
            bv[n] = __builtin_bit_cast(bf16x8,
                *(const us8*)(Wfw + (size_t)(kk * 4 + n) * 512 + l * 8));
#pragma unroll
        for (int m = 0; m < 4; m++) {
            int r = m * 16 + lo;
            af[m] = __builtin_bit_cast(bf16x8,
                *(const us8*)(AB + r * 512 + (kbyte ^ ((r & 7) << 4))));
        }
#pragma unroll
        for (int m = 0; m < 4; m++)
#pragma unroll
            for (int n = 0; n < 4; n++)
                acc[m][n] = __builtin_amdgcn_mfma_f32_16x16x32_bf16(
                    af[m], bv[n], acc[m][n], 0, 0, 0);
    }
}

__global__ __launch_bounds__(256) void resid_kernel(
    const u16* __restrict__ H, const u16* __restrict__ Wf,
    const float* __restrict__ Wout, const float* __restrict__ evec,
    const int* __restrict__ eidx, float* __restrict__ out) {
    __shared__ u16 xb[64 * 256];   // swizzled [row][col], 512B rows
    __shared__ u16 tb[64 * 256];
    __shared__ float fpart[4][64];
    const int t = threadIdx.x, w = t >> 6, l = t & 63;
    const int lo = l & 15, hi = l >> 4;
    const long rowbase = (long)blockIdx.x * 64;
    char* xbB = (char*)xb;
    char* tbB = (char*)tb;

    // async fill x tile (H already stored as the swizzled image)
    {
        const char* gH = (const char*)H + (size_t)blockIdx.x * 32768 +
                         w * 1024 + l * 16;
        char* xdst = xbB + w * 1024;
#pragma unroll
        for (int c = 0; c < 8; ++c) async16(xdst + c * 4096, gH + c * 4096);
    }
    __syncthreads();

    f32x4 acc[4][4];
    const u16* Wfw = Wf + w * 16384;

    // G1: t1 = ssilu(x @ W1a) -> tb
    gemm_lds(xbB, Wfw + 0 * 65536, l, lo, hi, acc);
#pragma unroll
    for (int m = 0; m < 4; m++)
#pragma unroll
        for (int n = 0; n < 4; n++)
#pragma unroll
            for (int j = 0; j < 4; j++) {
                int r = m * 16 + hi * 4 + j;
                int cc = w * 64 + n * 16 + lo;
                *(u16*)(tbB + r * 512 + ((cc * 2) ^ ((r & 7) << 4))) =
                    f2bf(ssilu(acc[m][n][j]));
            }
    __syncthreads();

    // G2: x = (x + ssilu(t1 @ W1b)) * INV_SQRT2 -> xb
    gemm_lds(tbB, Wfw + 1 * 65536, l, lo, hi, acc);
#pragma unroll
    for (int m = 0; m < 4; m++)
#pragma unroll
        for (int n = 0; n < 4; n++)
#pragma unroll
            for (int j = 0; j < 4; j++) {
                int r = m * 16 + hi * 4 + j;
                int cc = w * 64 + n * 16 + lo;
                char* p = xbB + r * 512 + ((cc * 2) ^ ((r & 7) << 4));
                float xn = (bf2f(*(u16*)p) + ssilu(acc[m][n][j])) * INV_SQRT2;
                *(u16*)p = f2bf(xn);
            }
    __syncthreads();

    // G3: t1 = ssilu(x @ W2a) -> tb
    gemm_lds(xbB, Wfw + 2 * 65536, l, lo, hi, acc);
#pragma unroll
    for (int m = 0; m < 4; m++)
#pragma unroll
        for (int n = 0; n < 4; n++)
#pragma unroll
            for (int j = 0; j < 4; j++) {
                int r = m * 16 + hi * 4 + j;
                int cc = w * 64 + n * 16 + lo;
                *(u16*)(tbB + r * 512 + ((cc * 2) ^ ((r & 7) << 4))) =
                    f2bf(ssilu(acc[m][n][j]));
            }
    __syncthreads();

    // G4: x_final = (x + ssilu(t1 @ W2b)) * INV_SQRT2, fp32 in regs
    gemm_lds(tbB, Wfw + 3 * 65536, l, lo, hi, acc);
    float wo[4];
#pragma unroll
    for (int n = 0; n < 4; n++) wo[n] = Wout[w * 64 + n * 16 + lo];

    float part[4][4];
#pragma unroll
    for (int m = 0; m < 4; m++)
#pragma unroll
        for (int j = 0; j < 4; j++) part[m][j] = 0.f;
#pragma unroll
    for (int m = 0; m < 4; m++)
#pragma unroll
        for (int n = 0; n < 4; n++)
#pragma unroll
            for (int j = 0; j < 4; j++) {
                int r = m * 16 + hi * 4 + j;
                int cc = w * 64 + n * 16 + lo;
                const char* p = xbB + r * 512 + ((cc * 2) ^ ((r & 7) << 4));
                float xf = (bf2f(*(const u16*)p) + ssilu(acc[m][n][j])) * INV_SQRT2;
                part[m][j] += xf * wo[n];
            }
#pragma unroll
    for (int m = 0; m < 4; m++)
#pragma unroll
        for (int j = 0; j < 4; j++) {
            float v = part[m][j];
            v += __shfl_xor(v, 1);
            v += __shfl_xor(v, 2);
            v += __shfl_xor(v, 4);
            v += __shfl_xor(v, 8);
            if (lo == 0) fpart[w][m * 16 + hi * 4 + j] = v;
        }
    __syncthreads();

    if (t < 64) {
        int r = t;
        float F = fpart[0][r] + fpart[1][r] + fpart[2][r] + fpart[3][r];
        long e = rowbase + r;
        float vx = evec[e * 3 + 0], vy = evec[e * 3 + 1], vz = evec[e * 3 + 2];
        int a = eidx[e];
        atomicAdd(&out[a * 3 + 0], F * vx);
        atomicAdd(&out[a * 3 + 1], F * vy);
        atomicAdd(&out[a * 3 + 2], F * vz);
    }
}

extern "C" void kernel_launch(void* const* d_in, const int* in_sizes, int n_in,
                              void* d_out, int out_size, void* d_ws, size_t ws_size,
                              hipStream_t stream) {
    const float* x_cat = (const float*)d_in[0];
    const float* evec  = (const float*)d_in[1];
    const int*   eidx  = (const int*)d_in[2];
    const float* Win   = (const float*)d_in[3];
    const float* W1a   = (const float*)d_in[4];
    const float* W1b   = (const float*)d_in[5];
    const float* W2a   = (const float*)d_in[6];
    const float* W2b   = (const float*)d_in[7];
    const float* Wout  = (const float*)d_in[8];
    float* out = (float*)d_out;
    const int E = in_sizes[1] / 3;   // 200000
    const int NB = E / 64;           // 3125

    u16* H     = (u16*)d_ws;                       // NB * 16384 elems (32KB/block)
    u16* WtInT = H + (size_t)NB * 16384;           // 327680 elems
    u16* Wfrag = WtInT + 327680;                   // 262144 elems

    int prepN = 327680 + 262144 + out_size;
    prep_kernel<<<(prepN + 255) / 256, 256, 0, stream>>>(
        Win, W1a, W1b, W2a, W2b, WtInT, Wfrag, out, out_size);
    gemm1_kernel<<<NB, 256, 0, stream>>>(x_cat, WtInT, H);
    resid_kernel<<<NB, 256, 0, stream>>>(H, Wfrag, Wout, evec, eidx, out);
}

// Round 4
// 590.080 us; speedup vs baseline: 1.5938x; 1.0558x over previous
//
#include <hip/hip_runtime.h>

typedef __attribute__((ext_vector_type(4))) float f32x4;
typedef __attribute__((ext_vector_type(8))) __bf16 bf16x8;
typedef __attribute__((ext_vector_type(8))) unsigned short us8;
typedef unsigned short u16;

#define SSILU_SCALE (1.0f / 0.6f)
#define INV_SQRT2 0.70710678118654752f

__device__ __forceinline__ u16 f2bf(float f) {
    __bf16 h = (__bf16)f;
    return __builtin_bit_cast(u16, h);
}
__device__ __forceinline__ float bf2f(u16 h) {
    union { unsigned int u; float f; } v; v.u = ((unsigned int)h) << 16;
    return v.f;
}
__device__ __forceinline__ float ssilu(float x) {
    return x / (1.0f + __expf(-x)) * SSILU_SCALE;
}
__device__ __forceinline__ void async16(void* lds, const void* g) {
    __builtin_amdgcn_global_load_lds(
        (const __attribute__((address_space(1))) unsigned int*)g,
        (__attribute__((address_space(3))) unsigned int*)lds, 16, 0, 0);
}

// ---------------------------------------------------------------------------
// prep (unchanged from round 3)
// ---------------------------------------------------------------------------
__global__ __launch_bounds__(256) void prep_kernel(
    const float* __restrict__ Win, const float* __restrict__ W1a,
    const float* __restrict__ W1b, const float* __restrict__ W2a,
    const float* __restrict__ W2b, u16* __restrict__ WtInT,
    u16* __restrict__ Wfrag, float* __restrict__ out, int outN) {
    int i = blockIdx.x * 256 + threadIdx.x;
    if (i < 327680) {                    // 20 tiles x 256 cols x 64 k
        int kt = i >> 14, r = i & 16383;
        int col = r >> 6, k = r & 63;
        int off = col * 128 + ((k * 2) ^ ((col & 7) << 4));
        WtInT[kt * 16384 + (off >> 1)] = f2bf(Win[(kt * 64 + k) * 256 + col]);
        return;
    }
    int j = i - 327680;
    if (j < 262144) {                    // 4 x 65536 -> [g][w][kk][n][lane][8]
        int g = j >> 16, r = j & 65535;
        int chunk = r >> 9, within = r & 511;
        int lane = within >> 3, e = within & 7;
        int w = chunk >> 5, kk = (chunk >> 2) & 7, n = chunk & 3;
        int lo = lane & 15, hi = lane >> 4;
        int col = w * 64 + n * 16 + lo;
        int k = kk * 32 + hi * 8 + e;
        const float* W = (g == 0) ? W1a : (g == 1) ? W1b : (g == 2) ? W2a : W2b;
        Wfrag[j] = f2bf(W[k * 256 + col]);
        return;
    }
    int z = j - 262144;
    if (z < outN) out[z] = 0.0f;
}

// ---------------------------------------------------------------------------
// gemm1: H_img = ssilu(x_cat @ W_in). Full double-buffer, counted vmcnt,
// raw barriers. A: fp32->bf16 reg-staged. B: async16 of pre-swizzled image.
// ---------------------------------------------------------------------------
__global__ __launch_bounds__(256, 2) void gemm1_kernel(
    const float* __restrict__ A, const u16* __restrict__ WtInT,
    u16* __restrict__ H) {
    __shared__ u16 Bs[2][256 * 64];   // 2 x 32KB swizzled B tiles
    __shared__ u16 As[2][64 * 64];    // 2 x 8KB swizzled A tiles
    const int t = threadIdx.x, w = t >> 6, l = t & 63;
    const int lo = l & 15, hi = l >> 4;
    const long rowbase = (long)blockIdx.x * 64;

    f32x4 acc[4][4];
#pragma unroll
    for (int m = 0; m < 4; m++)
#pragma unroll
        for (int n = 0; n < 4; n++) acc[m][n] = (f32x4){0.f, 0.f, 0.f, 0.f};

    float4 va[2][2];
    auto LOADA = [&](int kb) {
#pragma unroll
        for (int c = 0; c < 2; ++c) {
            int idx = t + c * 256;
            int r = idx >> 3, k8 = (idx & 7) * 8;
            const float* s = A + (rowbase + r) * 1280 + kb + k8;
            va[c][0] = *(const float4*)s;
            va[c][1] = *(const float4*)(s + 4);
        }
    };
    auto WRITEA = [&](char* dst) {
#pragma unroll
        for (int c = 0; c < 2; ++c) {
            int idx = t + c * 256;
            int r = idx >> 3, k8 = (idx & 7) * 8;
            us8 p;
            p[0] = f2bf(va[c][0].x); p[1] = f2bf(va[c][0].y);
            p[2] = f2bf(va[c][0].z); p[3] = f2bf(va[c][0].w);
            p[4] = f2bf(va[c][1].x); p[5] = f2bf(va[c][1].y);
            p[6] = f2bf(va[c][1].z); p[7] = f2bf(va[c][1].w);
            *(us8*)(dst + r * 128 + ((k8 * 2) ^ ((r & 7) << 4))) = p;
        }
    };
    auto ISSUEB = [&](int kt, char* dstBase) {
        const char* gsrc = (const char*)WtInT + (size_t)kt * 32768 +
                           w * 1024 + l * 16;
        char* ldst = dstBase + w * 1024;
#pragma unroll
        for (int c = 0; c < 8; ++c)
            async16(ldst + c * 4096, gsrc + c * 4096);
    };

    // prologue: tile 0 fully staged, drained, fenced
    LOADA(0);
    ISSUEB(0, (char*)Bs[0]);
    WRITEA((char*)As[0]);                       // compiler waits va
    asm volatile("s_waitcnt vmcnt(0) lgkmcnt(0)" ::: "memory");
    __builtin_amdgcn_s_barrier();

    for (int kt = 0; kt < 20; ++kt) {
        const int cur = kt & 1, nxt = cur ^ 1;
        const bool more = (kt + 1 < 20);
        if (more) {
            LOADA((kt + 1) * 64);               // 4 VMEM (oldest of new batch)
            __builtin_amdgcn_sched_barrier(0);
            ISSUEB(kt + 1, (char*)Bs[nxt]);     // 8 VMEM
            // outstanding: B(kt)[<=8] + A(kt+1)[4] + B(kt+1)[8]
            asm volatile("s_waitcnt vmcnt(12)" ::: "memory");  // B(kt) landed
        } else {
            asm volatile("s_waitcnt vmcnt(0)" ::: "memory");
        }
        __builtin_amdgcn_sched_barrier(0);

        const char* AB = (const char*)As[cur];
        const char* BB = (const char*)Bs[cur];
#pragma unroll
        for (int kk = 0; kk < 2; ++kk) {
            int kbyte = kk * 64 + hi * 16;
            bf16x8 af[4], bv[4];
#pragma unroll
            for (int m = 0; m < 4; m++) {
                int r = m * 16 + lo;
                af[m] = __builtin_bit_cast(bf16x8,
                    *(const us8*)(AB + r * 128 + (kbyte ^ ((r & 7) << 4))));
            }
#pragma unroll
            for (int n = 0; n < 4; n++) {
                int cc = w * 64 + n * 16 + lo;
                bv[n] = __builtin_bit_cast(bf16x8,
                    *(const us8*)(BB + cc * 128 + (kbyte ^ ((cc & 7) << 4))));
            }
#pragma unroll
            for (int m = 0; m < 4; m++)
#pragma unroll
                for (int n = 0; n < 4; n++)
                    acc[m][n] = __builtin_amdgcn_mfma_f32_16x16x32_bf16(
                        af[m], bv[n], acc[m][n], 0, 0, 0);
        }
        if (more) WRITEA((char*)As[nxt]);       // compiler waits A(kt+1) only
        asm volatile("s_waitcnt lgkmcnt(0)" ::: "memory");
        __builtin_amdgcn_s_barrier();
    }

    // epilogue: build swizzled H image in Bs[0], coalesced 32KB store
#pragma unroll
    for (int m = 0; m < 4; m++)
#pragma unroll
        for (int n = 0; n < 4; n++)
#pragma unroll
            for (int j = 0; j < 4; j++) {
                int r = m * 16 + hi * 4 + j;
                int cc = w * 64 + n * 16 + lo;
                *(u16*)((char*)Bs[0] + r * 512 + ((cc * 2) ^ ((r & 7) << 4))) =
                    f2bf(ssilu(acc[m][n][j]));
            }
    __syncthreads();
    char* dst = (char*)H + (size_t)blockIdx.x * 32768;
#pragma unroll
    for (int c = 0; c < 8; ++c) {
        int off = (t + c * 256) * 16;
        *(us8*)(dst + off) = *(const us8*)((char*)Bs[0] + off);
    }
}

// ---------------------------------------------------------------------------
// resid: B-fragment prefetch pipeline inside gemm_lds; rest as round 3.
// ---------------------------------------------------------------------------
__device__ __forceinline__ void gemm_lds(const char* AB, const u16* __restrict__ Wfw,
                                         int l, int lo, int hi, f32x4 acc[4][4]) {
#pragma unroll
    for (int m = 0; m < 4; m++)
#pragma unroll
        for (int n = 0; n < 4; n++) acc[m][n] = (f32x4){0.f, 0.f, 0.f, 0.f};
    bf16x8 bv[4];
#pragma unroll
    for (int n = 0; n < 4; n++)
        bv[n] = __builtin_bit_cast(bf16x8,
            *(const us8*)(Wfw + (size_t)n * 512 + l * 8));
#pragma unroll
    for (int kk = 0; kk < 8; ++kk) {
        int kbyte = kk * 64 + hi * 16;
        bf16x8 af[4], bvn[4];
#pragma unroll
        for (int m = 0; m < 4; m++) {
            int r = m * 16 + lo;
            af[m] = __builtin_bit_cast(bf16x8,
                *(const us8*)(AB + r * 512 + (kbyte ^ ((r & 7) << 4))));
        }
        if (kk < 7) {
#pragma unroll
            for (int n = 0; n < 4; n++)
                bvn[n] = __builtin_bit_cast(bf16x8,
                    *(const us8*)(Wfw + (size_t)((kk + 1) * 4 + n) * 512 + l * 8));
        }
#pragma unroll
        for (int m = 0; m < 4; m++)
#pragma unroll
            for (int n = 0; n < 4; n++)
                acc[m][n] = __builtin_amdgcn_mfma_f32_16x16x32_bf16(
                    af[m], bv[n], acc[m][n], 0, 0, 0);
        if (kk < 7) {
#pragma unroll
            for (int n = 0; n < 4; n++) bv[n] = bvn[n];
        }
    }
}

__global__ __launch_bounds__(256) void resid_kernel(
    const u16* __restrict__ H, const u16* __restrict__ Wf,
    const float* __restrict__ Wout, const float* __restrict__ evec,
    const int* __restrict__ eidx, float* __restrict__ out) {
    __shared__ u16 xb[64 * 256];   // swizzled [row][col], 512B rows
    __shared__ u16 tb[64 * 256];
    __shared__ float fpart[4][64];
    const int t = threadIdx.x, w = t >> 6, l = t & 63;
    const int lo = l & 15, hi = l >> 4;
    const long rowbase = (long)blockIdx.x * 64;
    char* xbB = (char*)xb;
    char* tbB = (char*)tb;

    {
        const char* gH = (const char*)H + (size_t)blockIdx.x * 32768 +
                         w * 1024 + l * 16;
        char* xdst = xbB + w * 1024;
#pragma unroll
        for (int c = 0; c < 8; ++c) async16(xdst + c * 4096, gH + c * 4096);
    }
    __syncthreads();

    f32x4 acc[4][4];
    const u16* Wfw = Wf + w * 16384;

    // G1: t1 = ssilu(x @ W1a) -> tb
    gemm_lds(xbB, Wfw + 0 * 65536, l, lo, hi, acc);
#pragma unroll
    for (int m = 0; m < 4; m++)
#pragma unroll
        for (int n = 0; n < 4; n++)
#pragma unroll
            for (int j = 0; j < 4; j++) {
                int r = m * 16 + hi * 4 + j;
                int cc = w * 64 + n * 16 + lo;
                *(u16*)(tbB + r * 512 + ((cc * 2) ^ ((r & 7) << 4))) =
                    f2bf(ssilu(acc[m][n][j]));
            }
    __syncthreads();

    // G2: x = (x + ssilu(t1 @ W1b)) * INV_SQRT2 -> xb
    gemm_lds(tbB, Wfw + 1 * 65536, l, lo, hi, acc);
#pragma unroll
    for (int m = 0; m < 4; m++)
#pragma unroll
        for (int n = 0; n < 4; n++)
#pragma unroll
            for (int j = 0; j < 4; j++) {
                int r = m * 16 + hi * 4 + j;
                int cc = w * 64 + n * 16 + lo;
                char* p = xbB + r * 512 + ((cc * 2) ^ ((r & 7) << 4));
                float xn = (bf2f(*(u16*)p) + ssilu(acc[m][n][j])) * INV_SQRT2;
                *(u16*)p = f2bf(xn);
            }
    __syncthreads();

    // G3: t1 = ssilu(x @ W2a) -> tb
    gemm_lds(xbB, Wfw + 2 * 65536, l, lo, hi, acc);
#pragma unroll
    for (int m = 0; m < 4; m++)
#pragma unroll
        for (int n = 0; n < 4; n++)
#pragma unroll
            for (int j = 0; j < 4; j++) {
                int r = m * 16 + hi * 4 + j;
                int cc = w * 64 + n * 16 + lo;
                *(u16*)(tbB + r * 512 + ((cc * 2) ^ ((r & 7) << 4))) =
                    f2bf(ssilu(acc[m][n][j]));
            }
    __syncthreads();

    // G4: x_final = (x + ssilu(t1 @ W2b)) * INV_SQRT2, fp32 in regs
    gemm_lds(tbB, Wfw + 3 * 65536, l, lo, hi, acc);
    float wo[4];
#pragma unroll
    for (int n = 0; n < 4; n++) wo[n] = Wout[w * 64 + n * 16 + lo];

    float part[4][4];
#pragma unroll
    for (int m = 0; m < 4; m++)
#pragma unroll
        for (int j = 0; j < 4; j++) part[m][j] = 0.f;
#pragma unroll
    for (int m = 0; m < 4; m++)
#pragma unroll
        for (int n = 0; n < 4; n++)
#pragma unroll
            for (int j = 0; j < 4; j++) {
                int r = m * 16 + hi * 4 + j;
                int cc = w * 64 + n * 16 + lo;
                const char* p = xbB + r * 512 + ((cc * 2) ^ ((r & 7) << 4));
                float xf = (bf2f(*(const u16*)p) + ssilu(acc[m][n][j])) * INV_SQRT2;
                part[m][j] += xf * wo[n];
            }
#pragma unroll
    for (int m = 0; m < 4; m++)
#pragma unroll
        for (int j = 0; j < 4; j++) {
            float v = part[m][j];
            v += __shfl_xor(v, 1);
            v += __shfl_xor(v, 2);
            v += __shfl_xor(v, 4);
            v += __shfl_xor(v, 8);
            if (lo == 0) fpart[w][m * 16 + hi * 4 + j] = v;
        }
    __syncthreads();

    if (t < 64) {
        int r = t;
        float F = fpart[0][r] + fpart[1][r] + fpart[2][r] + fpart[3][r];
        long e = rowbase + r;
        float vx = evec[e * 3 + 0], vy = evec[e * 3 + 1], vz = evec[e * 3 + 2];
        int a = eidx[e];
        atomicAdd(&out[a * 3 + 0], F * vx);
        atomicAdd(&out[a * 3 + 1], F * vy);
        atomicAdd(&out[a * 3 + 2], F * vz);
    }
}

extern "C" void kernel_launch(void* const* d_in, const int* in_sizes, int n_in,
                              void* d_out, int out_size, void* d_ws, size_t ws_size,
                              hipStream_t stream) {
    const float* x_cat = (const float*)d_in[0];
    const float* evec  = (const float*)d_in[1];
    const int*   eidx  = (const int*)d_in[2];
    const float* Win   = (const float*)d_in[3];
    const float* W1a   = (const float*)d_in[4];
    const float* W1b   = (const float*)d_in[5];
    const float* W2a   = (const float*)d_in[6];
    const float* W2b   = (const float*)d_in[7];
    const float* Wout  = (const float*)d_in[8];
    float* out = (float*)d_out;
    const int E = in_sizes[1] / 3;   // 200000
    const int NB = E / 64;           // 3125

    u16* H     = (u16*)d_ws;                       // NB * 16384 elems
    u16* WtInT = H + (size_t)NB * 16384;           // 327680 elems
    u16* Wfrag = WtInT + 327680;                   // 262144 elems

    int prepN = 327680 + 262144 + out_size;
    prep_kernel<<<(prepN + 255) / 256, 256, 0, stream>>>(
        Win, W1a, W1b, W2a, W2b, WtInT, Wfrag, out, out_size);
    gemm1_kernel<<<NB, 256, 0, stream>>>(x_cat, WtInT, H);
    resid_kernel<<<NB, 256, 0, stream>>>(H, Wfrag, Wout, evec, eidx, out);
}

// Round 5
// 467.094 us; speedup vs baseline: 2.0135x; 1.2633x over previous
//
#include <hip/hip_runtime.h>

typedef __attribute__((ext_vector_type(4))) float f32x4;
typedef __attribute__((ext_vector_type(8))) __bf16 bf16x8;
typedef __attribute__((ext_vector_type(8))) unsigned short us8;
typedef unsigned short u16;

#define SSILU_SCALE (1.0f / 0.6f)
#define INV_SQRT2 0.70710678118654752f

__device__ __forceinline__ u16 f2bf(float f) {
    __bf16 h = (__bf16)f;
    return __builtin_bit_cast(u16, h);
}
__device__ __forceinline__ float bf2f(u16 h) {
    union { unsigned int u; float f; } v; v.u = ((unsigned int)h) << 16;
    return v.f;
}
__device__ __forceinline__ float ssilu(float x) {
    float e = __expf(-x);
    float s = __builtin_amdgcn_rcpf(1.0f + e);   // v_rcp_f32, exact to bf16
    return x * s * SSILU_SCALE;
}
__device__ __forceinline__ void async16(void* lds, const void* g) {
    __builtin_amdgcn_global_load_lds(
        (const __attribute__((address_space(1))) unsigned int*)g,
        (__attribute__((address_space(3))) unsigned int*)lds, 16, 0, 0);
}

// ---------------------------------------------------------------------------
// prep:
//  WinF : W_in as MFMA B-fragments [kt][w][kk][n][lane][8] (1KB wave chunks)
//  Wfrag: 4 resid matrices as [g][w][kk][n][lane][8]
//  out  : zeroed
// ---------------------------------------------------------------------------
__global__ __launch_bounds__(256) void prep_kernel(
    const float* __restrict__ Win, const float* __restrict__ W1a,
    const float* __restrict__ W1b, const float* __restrict__ W2a,
    const float* __restrict__ W2b, u16* __restrict__ WinF,
    u16* __restrict__ Wfrag, float* __restrict__ out, int outN) {
    int i = blockIdx.x * 256 + threadIdx.x;
    if (i < 327680) {                    // 20 kt x 4 w x 2 kk x 4 n x 64 lane x 8
        int e = i & 7, lane = (i >> 3) & 63, n = (i >> 9) & 3;
        int kk = (i >> 11) & 1, w = (i >> 12) & 3, kt = i >> 14;
        int lo = lane & 15, hi = lane >> 4;
        int k = kt * 64 + kk * 32 + hi * 8 + e;
        int col = w * 64 + n * 16 + lo;
        WinF[i] = f2bf(Win[k * 256 + col]);
        return;
    }
    int j = i - 327680;
    if (j < 262144) {                    // 4 x [w(4)][kk(8)][n(4)][lane][8]
        int g = j >> 16, r = j & 65535;
        int chunk = r >> 9, within = r & 511;
        int lane = within >> 3, e = within & 7;
        int w = chunk >> 5, kk = (chunk >> 2) & 7, n = chunk & 3;
        int lo = lane & 15, hi = lane >> 4;
        int col = w * 64 + n * 16 + lo;
        int k = kk * 32 + hi * 8 + e;
        const float* W = (g == 0) ? W1a : (g == 1) ? W1b : (g == 2) ? W2a : W2b;
        Wfrag[j] = f2bf(W[k * 256 + col]);
        return;
    }
    int z = j - 262144;
    if (z < outN) out[z] = 0.0f;
}

// ---------------------------------------------------------------------------
// gemm1: H = ssilu(x_cat @ W_in). 64 rows x 256 cols per block.
// A: fp32->bf16 reg-staged into 2x8KB LDS (only barrier). B: direct coalesced
// reg loads from WinF, prefetched one K-step ahead (2 named reg sets).
// No vmcnt drain anywhere in the loop. H stored as 16KB/32-row images.
// ---------------------------------------------------------------------------
__global__ __launch_bounds__(256, 2) void gemm1_kernel(
    const float* __restrict__ A, const u16* __restrict__ WinF,
    u16* __restrict__ H) {
    __shared__ u16 As[2][64 * 64];    // 2 x 8KB swizzled A tiles; epilogue bounce
    const int t = threadIdx.x, w = t >> 6, l = t & 63;
    const int lo = l & 15, hi = l >> 4;
    const long rowbase = (long)blockIdx.x * 64;

    f32x4 acc[4][4];
#pragma unroll
    for (int m = 0; m < 4; m++)
#pragma unroll
        for (int n = 0; n < 4; n++) acc[m][n] = (f32x4){0.f, 0.f, 0.f, 0.f};

    float4 va[2][2];
    auto LOADA = [&](int kb) {
#pragma unroll
        for (int c = 0; c < 2; ++c) {
            int idx = t + c * 256;
            int r = idx >> 3, k8 = (idx & 7) * 8;
            const float* s = A + (rowbase + r) * 1280 + kb + k8;
            va[c][0] = *(const float4*)s;
            va[c][1] = *(const float4*)(s + 4);
        }
    };
    auto WRITEA = [&](char* dst) {
#pragma unroll
        for (int c = 0; c < 2; ++c) {
            int idx = t + c * 256;
            int r = idx >> 3, k8 = (idx & 7) * 8;
            us8 p;
            p[0] = f2bf(va[c][0].x); p[1] = f2bf(va[c][0].y);
            p[2] = f2bf(va[c][0].z); p[3] = f2bf(va[c][0].w);
            p[4] = f2bf(va[c][1].x); p[5] = f2bf(va[c][1].y);
            p[6] = f2bf(va[c][1].z); p[7] = f2bf(va[c][1].w);
            *(us8*)(dst + r * 128 + ((k8 * 2) ^ ((r & 7) << 4))) = p;
        }
    };
    auto LOADB = [&](int kt, bf16x8 (&b)[8]) {
        const u16* base = WinF + kt * 16384 + w * 4096 + l * 8;
#pragma unroll
        for (int kk = 0; kk < 2; ++kk)
#pragma unroll
            for (int n = 0; n < 4; ++n)
                b[kk * 4 + n] = __builtin_bit_cast(bf16x8,
                    *(const us8*)(base + kk * 2048 + n * 512));
    };

    bf16x8 b0[8], b1[8];

    auto STEP = [&](int kt, const char* ABcur, char* ABnxt,
                    bf16x8 (&bc)[8], bf16x8 (&bn)[8]) {
        const bool more = (kt + 1 < 20);
        if (more) {
            LOADA((kt + 1) * 64);        // 4 VMEM (A, HBM)
            LOADB(kt + 1, bn);           // 8 VMEM (B, L2-hot)
        }
#pragma unroll
        for (int kk = 0; kk < 2; ++kk) {
            int kbyte = kk * 64 + hi * 16;
            bf16x8 af[4];
#pragma unroll
            for (int m = 0; m < 4; m++) {
                int r = m * 16 + lo;
                af[m] = __builtin_bit_cast(bf16x8,
                    *(const us8*)(ABcur + r * 128 + (kbyte ^ ((r & 7) << 4))));
            }
#pragma unroll
            for (int m = 0; m < 4; m++)
#pragma unroll
                for (int n = 0; n < 4; n++)
                    acc[m][n] = __builtin_amdgcn_mfma_f32_16x16x32_bf16(
                        af[m], bc[kk * 4 + n], acc[m][n], 0, 0, 0);
        }
        if (more) WRITEA(ABnxt);         // waits only A(kt+1) loads (vmcnt 8)
        asm volatile("s_waitcnt lgkmcnt(0)" ::: "memory");
        __builtin_amdgcn_sched_barrier(0);
        __builtin_amdgcn_s_barrier();
    };

    // prologue: A(0) staged, B(0) in regs
    LOADA(0);
    LOADB(0, b0);
    WRITEA((char*)As[0]);
    asm volatile("s_waitcnt lgkmcnt(0)" ::: "memory");
    __builtin_amdgcn_s_barrier();

    for (int i = 0; i < 10; ++i) {
        STEP(2 * i,     (const char*)As[0], (char*)As[1], b0, b1);
        STEP(2 * i + 1, (const char*)As[1], (char*)As[0], b1, b0);
    }

    // epilogue: two 32-row halves through the 16KB As bounce, coalesced store
    char* bounce = (char*)As;
#pragma unroll
    for (int half = 0; half < 2; ++half) {
#pragma unroll
        for (int m2 = 0; m2 < 2; ++m2) {
            int m = half * 2 + m2;
#pragma unroll
            for (int n = 0; n < 4; n++)
#pragma unroll
                for (int j = 0; j < 4; j++) {
                    int r = m2 * 16 + hi * 4 + j;       // row within 32
                    int cc = w * 64 + n * 16 + lo;
                    *(u16*)(bounce + r * 512 + ((cc * 2) ^ ((r & 7) << 4))) =
                        f2bf(ssilu(acc[m][n][j]));
                }
        }
        __syncthreads();
        char* dst = (char*)H + ((size_t)blockIdx.x * 2 + half) * 16384;
#pragma unroll
        for (int c = 0; c < 4; ++c) {
            int off = (t + c * 256) * 16;
            *(us8*)(dst + off) = *(const us8*)(bounce + off);
        }
        __syncthreads();
    }
}

// ---------------------------------------------------------------------------
// resid: 32-row tiles (4 blocks/CU). 2 residual blocks + W_out + scatter-add.
// ---------------------------------------------------------------------------
__device__ __forceinline__ void gemm_lds(const char* AB, const u16* __restrict__ Wfw,
                                         int l, int lo, int hi, f32x4 acc[2][4]) {
#pragma unroll
    for (int m = 0; m < 2; m++)
#pragma unroll
        for (int n = 0; n < 4; n++) acc[m][n] = (f32x4){0.f, 0.f, 0.f, 0.f};
    bf16x8 bv[4];
#pragma unroll
    for (int n = 0; n < 4; n++)
        bv[n] = __builtin_bit_cast(bf16x8,
            *(const us8*)(Wfw + (size_t)n * 512 + l * 8));
#pragma unroll
    for (int kk = 0; kk < 8; ++kk) {
        int kbyte = kk * 64 + hi * 16;
        bf16x8 af[2], bvn[4];
#pragma unroll
        for (int m = 0; m < 2; m++) {
            int r = m * 16 + lo;
            af[m] = __builtin_bit_cast(bf16x8,
                *(const us8*)(AB + r * 512 + (kbyte ^ ((r & 7) << 4))));
        }
        if (kk < 7) {
#pragma unroll
            for (int n = 0; n < 4; n++)
                bvn[n] = __builtin_bit_cast(bf16x8,
                    *(const us8*)(Wfw + (size_t)((kk + 1) * 4 + n) * 512 + l * 8));
        }
#pragma unroll
        for (int m = 0; m < 2; m++)
#pragma unroll
            for (int n = 0; n < 4; n++)
                acc[m][n] = __builtin_amdgcn_mfma_f32_16x16x32_bf16(
                    af[m], bv[n], acc[m][n], 0, 0, 0);
        if (kk < 7) {
#pragma unroll
            for (int n = 0; n < 4; n++) bv[n] = bvn[n];
        }
    }
}

__global__ __launch_bounds__(256, 4) void resid_kernel(
    const u16* __restrict__ H, const u16* __restrict__ Wf,
    const float* __restrict__ Wout, const float* __restrict__ evec,
    const int* __restrict__ eidx, float* __restrict__ out) {
    __shared__ u16 xb[32 * 256];   // swizzled [row][col], 512B rows (16KB)
    __shared__ u16 tb[32 * 256];
    __shared__ float fpart[4][32];
    const int t = threadIdx.x, w = t >> 6, l = t & 63;
    const int lo = l & 15, hi = l >> 4;
    const long rowbase = (long)blockIdx.x * 32;
    char* xbB = (char*)xb;
    char* tbB = (char*)tb;

    // async fill x tile (H stored as the swizzled 16KB image)
    {
        const char* gH = (const char*)H + (size_t)blockIdx.x * 16384 +
                         w * 1024 + l * 16;
        char* xdst = xbB + w * 1024;
#pragma unroll
        for (int c = 0; c < 4; ++c) async16(xdst + c * 4096, gH + c * 4096);
    }
    __syncthreads();

    f32x4 acc[2][4];
    const u16* Wfw = Wf + w * 16384;

    // G1: t1 = ssilu(x @ W1a) -> tb
    gemm_lds(xbB, Wfw + 0 * 65536, l, lo, hi, acc);
#pragma unroll
    for (int m = 0; m < 2; m++)
#pragma unroll
        for (int n = 0; n < 4; n++)
#pragma unroll
            for (int j = 0; j < 4; j++) {
                int r = m * 16 + hi * 4 + j;
                int cc = w * 64 + n * 16 + lo;
                *(u16*)(tbB + r * 512 + ((cc * 2) ^ ((r & 7) << 4))) =
                    f2bf(ssilu(acc[m][n][j]));
            }
    __syncthreads();

    // G2: x = (x + ssilu(t1 @ W1b)) * INV_SQRT2 -> xb
    gemm_lds(tbB, Wfw + 1 * 65536, l, lo, hi, acc);
#pragma unroll
    for (int m = 0; m < 2; m++)
#pragma unroll
        for (int n = 0; n < 4; n++)
#pragma unroll
            for (int j = 0; j < 4; j++) {
                int r = m * 16 + hi * 4 + j;
                int cc = w * 64 + n * 16 + lo;
                char* p = xbB + r * 512 + ((cc * 2) ^ ((r & 7) << 4));
                float xn = (bf2f(*(u16*)p) + ssilu(acc[m][n][j])) * INV_SQRT2;
                *(u16*)p = f2bf(xn);
            }
    __syncthreads();

    // G3: t1 = ssilu(x @ W2a) -> tb
    gemm_lds(xbB, Wfw + 2 * 65536, l, lo, hi, acc);
#pragma unroll
    for (int m = 0; m < 2; m++)
#pragma unroll
        for (int n = 0; n < 4; n++)
#pragma unroll
            for (int j = 0; j < 4; j++) {
                int r = m * 16 + hi * 4 + j;
                int cc = w * 64 + n * 16 + lo;
                *(u16*)(tbB + r * 512 + ((cc * 2) ^ ((r & 7) << 4))) =
                    f2bf(ssilu(acc[m][n][j]));
            }
    __syncthreads();

    // G4: x_final = (x + ssilu(t1 @ W2b)) * INV_SQRT2, fp32 in regs
    gemm_lds(tbB, Wfw + 3 * 65536, l, lo, hi, acc);
    float wo[4];
#pragma unroll
    for (int n = 0; n < 4; n++) wo[n] = Wout[w * 64 + n * 16 + lo];

    float part[2][4];
#pragma unroll
    for (int m = 0; m < 2; m++)
#pragma unroll
        for (int j = 0; j < 4; j++) part[m][j] = 0.f;
#pragma unroll
    for (int m = 0; m < 2; m++)
#pragma unroll
        for (int n = 0; n < 4; n++)
#pragma unroll
            for (int j = 0; j < 4; j++) {
                int r = m * 16 + hi * 4 + j;
                int cc = w * 64 + n * 16 + lo;
                const char* p = xbB + r * 512 + ((cc * 2) ^ ((r & 7) << 4));
                float xf = (bf2f(*(const u16*)p) + ssilu(acc[m][n][j])) * INV_SQRT2;
                part[m][j] += xf * wo[n];
            }
#pragma unroll
    for (int m = 0; m < 2; m++)
#pragma unroll
        for (int j = 0; j < 4; j++) {
            float v = part[m][j];
            v += __shfl_xor(v, 1);
            v += __shfl_xor(v, 2);
            v += __shfl_xor(v, 4);
            v += __shfl_xor(v, 8);
            if (lo == 0) fpart[w][m * 16 + hi * 4 + j] = v;
        }
    __syncthreads();

    if (t < 32) {
        int r = t;
        float F = fpart[0][r] + fpart[1][r] + fpart[2][r] + fpart[3][r];
        long e = rowbase + r;
        float vx = evec[e * 3 + 0], vy = evec[e * 3 + 1], vz = evec[e * 3 + 2];
        int a = eidx[e];
        atomicAdd(&out[a * 3 + 0], F * vx);
        atomicAdd(&out[a * 3 + 1], F * vy);
        atomicAdd(&out[a * 3 + 2], F * vz);
    }
}

extern "C" void kernel_launch(void* const* d_in, const int* in_sizes, int n_in,
                              void* d_out, int out_size, void* d_ws, size_t ws_size,
                              hipStream_t stream) {
    const float* x_cat = (const float*)d_in[0];
    const float* evec  = (const float*)d_in[1];
    const int*   eidx  = (const int*)d_in[2];
    const float* Win   = (const float*)d_in[3];
    const float* W1a   = (const float*)d_in[4];
    const float* W1b   = (const float*)d_in[5];
    const float* W2a   = (const float*)d_in[6];
    const float* W2b   = (const float*)d_in[7];
    const float* Wout  = (const float*)d_in[8];
    float* out = (float*)d_out;
    const int E = in_sizes[1] / 3;   // 200000

    u16* H    = (u16*)d_ws;                       // E*256 u16 (16KB / 32 rows)
    u16* WinF = H + (size_t)E * 256;              // 327680 elems
    u16* Wfrag = WinF + 327680;                   // 262144 elems

    int prepN = 327680 + 262144 + out_size;
    prep_kernel<<<(prepN + 255) / 256, 256, 0, stream>>>(
        Win, W1a, W1b, W2a, W2b, WinF, Wfrag, out, out_size);
    gemm1_kernel<<<E / 64, 256, 0, stream>>>(x_cat, WinF, H);
    resid_kernel<<<E / 32, 256, 0, stream>>>(H, Wfrag, Wout, evec, eidx, out);
}

// Round 6
// 406.240 us; speedup vs baseline: 2.3151x; 1.1498x over previous
//
#include <hip/hip_runtime.h>

typedef __attribute__((ext_vector_type(4))) float f32x4;
typedef __attribute__((ext_vector_type(8))) __bf16 bf16x8;
typedef __attribute__((ext_vector_type(8))) unsigned short us8;
typedef unsigned short u16;

#define SSILU_SCALE (1.0f / 0.6f)
#define INV_SQRT2 0.70710678118654752f

__device__ __forceinline__ u16 f2bf(float f) {
    __bf16 h = (__bf16)f;
    return __builtin_bit_cast(u16, h);
}
__device__ __forceinline__ float bf2f(u16 h) {
    union { unsigned int u; float f; } v; v.u = ((unsigned int)h) << 16;
    return v.f;
}
__device__ __forceinline__ float ssilu(float x) {
    float e = __expf(-x);
    float s = __builtin_amdgcn_rcpf(1.0f + e);
    return x * s * SSILU_SCALE;
}

// ---------------------------------------------------------------------------
// prep:
//  WinF : W_in as MFMA B-fragments [kt][w][kk][n][lane][8] (1KB wave chunks)
//  Wfrag: 4 resid matrices as [g][w][kk][n][lane][8]
//  out  : zeroed
// ---------------------------------------------------------------------------
__global__ __launch_bounds__(256) void prep_kernel(
    const float* __restrict__ Win, const float* __restrict__ W1a,
    const float* __restrict__ W1b, const float* __restrict__ W2a,
    const float* __restrict__ W2b, u16* __restrict__ WinF,
    u16* __restrict__ Wfrag, float* __restrict__ out, int outN) {
    int i = blockIdx.x * 256 + threadIdx.x;
    if (i < 327680) {                    // 20 kt x 4 w x 2 kk x 4 n x 64 lane x 8
        int e = i & 7, lane = (i >> 3) & 63, n = (i >> 9) & 3;
        int kk = (i >> 11) & 1, w = (i >> 12) & 3, kt = i >> 14;
        int lo = lane & 15, hi = lane >> 4;
        int k = kt * 64 + kk * 32 + hi * 8 + e;
        int col = w * 64 + n * 16 + lo;
        WinF[i] = f2bf(Win[k * 256 + col]);
        return;
    }
    int j = i - 327680;
    if (j < 262144) {                    // 4 x [w(4)][kk(8)][n(4)][lane][8]
        int g = j >> 16, r = j & 65535;
        int chunk = r >> 9, within = r & 511;
        int lane = within >> 3, e = within & 7;
        int w = chunk >> 5, kk = (chunk >> 2) & 7, n = chunk & 3;
        int lo = lane & 15, hi = lane >> 4;
        int col = w * 64 + n * 16 + lo;
        int k = kk * 32 + hi * 8 + e;
        const float* W = (g == 0) ? W1a : (g == 1) ? W1b : (g == 2) ? W2a : W2b;
        Wfrag[j] = f2bf(W[k * 256 + col]);
        return;
    }
    int z = j - 262144;
    if (z < outN) out[z] = 0.0f;
}

// ---------------------------------------------------------------------------
// 64x256 tile GEMM on swizzled LDS x-tile; B streams coalesced from Wfrag.
// ---------------------------------------------------------------------------
__device__ __forceinline__ void gemm_lds(const char* AB, const u16* __restrict__ Wfw,
                                         int l, int lo, int hi, f32x4 acc[4][4]) {
#pragma unroll
    for (int m = 0; m < 4; m++)
#pragma unroll
        for (int n = 0; n < 4; n++) acc[m][n] = (f32x4){0.f, 0.f, 0.f, 0.f};
    bf16x8 bv[4];
#pragma unroll
    for (int n = 0; n < 4; n++)
        bv[n] = __builtin_bit_cast(bf16x8,
            *(const us8*)(Wfw + (size_t)n * 512 + l * 8));
#pragma unroll
    for (int kk = 0; kk < 8; ++kk) {
        int kbyte = kk * 64 + hi * 16;
        bf16x8 af[4], bvn[4];
#pragma unroll
        for (int m = 0; m < 4; m++) {
            int r = m * 16 + lo;
            af[m] = __builtin_bit_cast(bf16x8,
                *(const us8*)(AB + r * 512 + (kbyte ^ ((r & 7) << 4))));
        }
        if (kk < 7) {
#pragma unroll
            for (int n = 0; n < 4; n++)
                bvn[n] = __builtin_bit_cast(bf16x8,
                    *(const us8*)(Wfw + (size_t)((kk + 1) * 4 + n) * 512 + l * 8));
        }
#pragma unroll
        for (int m = 0; m < 4; m++)
#pragma unroll
            for (int n = 0; n < 4; n++)
                acc[m][n] = __builtin_amdgcn_mfma_f32_16x16x32_bf16(
                    af[m], bv[n], acc[m][n], 0, 0, 0);
        if (kk < 7) {
#pragma unroll
            for (int n = 0; n < 4; n++) bv[n] = bvn[n];
        }
    }
}

// ---------------------------------------------------------------------------
// fused: phase 1 = ssilu(x_cat @ W_in) -> xb (LDS, swizzled, no H roundtrip)
//        phase 2 = 2 residual blocks + W_out dot + scatter-add
// Block: 64 edge-rows, 4 waves. A-staging dbuf aliases tb (dead in phase 1).
// ---------------------------------------------------------------------------
__global__ __launch_bounds__(256, 2) void fused_kernel(
    const float* __restrict__ A, const u16* __restrict__ WinF,
    const u16* __restrict__ Wfrag, const float* __restrict__ Wout,
    const float* __restrict__ evec, const int* __restrict__ eidx,
    float* __restrict__ out) {
    __shared__ u16 xb[64 * 256];   // 32KB swizzled x tile (512B rows)
    __shared__ u16 tb[64 * 256];   // 32KB temp; first 16KB = A dbuf in phase 1
    __shared__ float fpart[4][64];
    const int t = threadIdx.x, w = t >> 6, l = t & 63;
    const int lo = l & 15, hi = l >> 4;
    const long rowbase = (long)blockIdx.x * 64;
    char* xbB = (char*)xb;
    char* tbB = (char*)tb;
    char* As0 = (char*)tb;
    char* As1 = (char*)tb + 8192;

    f32x4 acc[4][4];
#pragma unroll
    for (int m = 0; m < 4; m++)
#pragma unroll
        for (int n = 0; n < 4; n++) acc[m][n] = (f32x4){0.f, 0.f, 0.f, 0.f};

    // ---------------- phase 1 ----------------
    float4 va[2][2];
    auto LOADA = [&](int kb) {
#pragma unroll
        for (int c = 0; c < 2; ++c) {
            int idx = t + c * 256;
            int r = idx >> 3, k8 = (idx & 7) * 8;
            const float* s = A + (rowbase + r) * 1280 + kb + k8;
            va[c][0] = *(const float4*)s;
            va[c][1] = *(const float4*)(s + 4);
        }
    };
    auto WRITEA = [&](char* dst) {
#pragma unroll
        for (int c = 0; c < 2; ++c) {
            int idx = t + c * 256;
            int r = idx >> 3, k8 = (idx & 7) * 8;
            us8 p;
            p[0] = f2bf(va[c][0].x); p[1] = f2bf(va[c][0].y);
            p[2] = f2bf(va[c][0].z); p[3] = f2bf(va[c][0].w);
            p[4] = f2bf(va[c][1].x); p[5] = f2bf(va[c][1].y);
            p[6] = f2bf(va[c][1].z); p[7] = f2bf(va[c][1].w);
            *(us8*)(dst + r * 128 + ((k8 * 2) ^ ((r & 7) << 4))) = p;
        }
    };
    auto LOADB = [&](int kt, bf16x8 (&b)[8]) {
        const u16* base = WinF + kt * 16384 + w * 4096 + l * 8;
#pragma unroll
        for (int kk = 0; kk < 2; ++kk)
#pragma unroll
            for (int n = 0; n < 4; ++n)
                b[kk * 4 + n] = __builtin_bit_cast(bf16x8,
                    *(const us8*)(base + kk * 2048 + n * 512));
    };

    bf16x8 b0[8], b1[8];

    auto STEP = [&](int kt, const char* ABcur, char* ABnxt,
                    bf16x8 (&bc)[8], bf16x8 (&bn)[8]) {
        const bool more = (kt + 1 < 20);
        if (more) {
            LOADA((kt + 1) * 64);        // 4 VMEM (A, HBM)
            LOADB(kt + 1, bn);           // 8 VMEM (B, L2-hot)
        }
#pragma unroll
        for (int kk = 0; kk < 2; ++kk) {
            int kbyte = kk * 64 + hi * 16;
            bf16x8 af[4];
#pragma unroll
            for (int m = 0; m < 4; m++) {
                int r = m * 16 + lo;
                af[m] = __builtin_bit_cast(bf16x8,
                    *(const us8*)(ABcur + r * 128 + (kbyte ^ ((r & 7) << 4))));
            }
#pragma unroll
            for (int m = 0; m < 4; m++)
#pragma unroll
                for (int n = 0; n < 4; n++)
                    acc[m][n] = __builtin_amdgcn_mfma_f32_16x16x32_bf16(
                        af[m], bc[kk * 4 + n], acc[m][n], 0, 0, 0);
        }
        if (more) WRITEA(ABnxt);         // waits only the A(kt+1) loads
        asm volatile("s_waitcnt lgkmcnt(0)" ::: "memory");
        __builtin_amdgcn_sched_barrier(0);
        __builtin_amdgcn_s_barrier();
    };

    LOADA(0);
    LOADB(0, b0);
    WRITEA(As0);
    asm volatile("s_waitcnt lgkmcnt(0)" ::: "memory");
    __builtin_amdgcn_s_barrier();

    for (int i = 0; i < 10; ++i) {
        STEP(2 * i,     As0, As1, b0, b1);
        STEP(2 * i + 1, As1, As0, b1, b0);
    }

    // epilogue: x = ssilu(acc) -> xb (swizzled); tb's A-staging role ends here
#pragma unroll
    for (int m = 0; m < 4; m++)
#pragma unroll
        for (int n = 0; n < 4; n++)
#pragma unroll
            for (int j = 0; j < 4; j++) {
                int r = m * 16 + hi * 4 + j;
                int cc = w * 64 + n * 16 + lo;
                *(u16*)(xbB + r * 512 + ((cc * 2) ^ ((r & 7) << 4))) =
                    f2bf(ssilu(acc[m][n][j]));
            }
    __syncthreads();

    // ---------------- phase 2 ----------------
    const u16* Wfw = Wfrag + w * 16384;

    // G1: t1 = ssilu(x @ W1a) -> tb
    gemm_lds(xbB, Wfw + 0 * 65536, l, lo, hi, acc);
#pragma unroll
    for (int m = 0; m < 4; m++)
#pragma unroll
        for (int n = 0; n < 4; n++)
#pragma unroll
            for (int j = 0; j < 4; j++) {
                int r = m * 16 + hi * 4 + j;
                int cc = w * 64 + n * 16 + lo;
                *(u16*)(tbB + r * 512 + ((cc * 2) ^ ((r & 7) << 4))) =
                    f2bf(ssilu(acc[m][n][j]));
            }
    __syncthreads();

    // G2: x = (x + ssilu(t1 @ W1b)) * INV_SQRT2 -> xb
    gemm_lds(tbB, Wfw + 1 * 65536, l, lo, hi, acc);
#pragma unroll
    for (int m = 0; m < 4; m++)
#pragma unroll
        for (int n = 0; n < 4; n++)
#pragma unroll
            for (int j = 0; j < 4; j++) {
                int r = m * 16 + hi * 4 + j;
                int cc = w * 64 + n * 16 + lo;
                char* p = xbB + r * 512 + ((cc * 2) ^ ((r & 7) << 4));
                float xn = (bf2f(*(u16*)p) + ssilu(acc[m][n][j])) * INV_SQRT2;
                *(u16*)p = f2bf(xn);
            }
    __syncthreads();

    // G3: t1 = ssilu(x @ W2a) -> tb
    gemm_lds(xbB, Wfw + 2 * 65536, l, lo, hi, acc);
#pragma unroll
    for (int m = 0; m < 4; m++)
#pragma unroll
        for (int n = 0; n < 4; n++)
#pragma unroll
            for (int j = 0; j < 4; j++) {
                int r = m * 16 + hi * 4 + j;
                int cc = w * 64 + n * 16 + lo;
                *(u16*)(tbB + r * 512 + ((cc * 2) ^ ((r & 7) << 4))) =
                    f2bf(ssilu(acc[m][n][j]));
            }
    __syncthreads();

    // G4: x_final = (x + ssilu(t1 @ W2b)) * INV_SQRT2, fp32 in regs
    gemm_lds(tbB, Wfw + 3 * 65536, l, lo, hi, acc);
    float wo[4];
#pragma unroll
    for (int n = 0; n < 4; n++) wo[n] = Wout[w * 64 + n * 16 + lo];

    float part[4][4];
#pragma unroll
    for (int m = 0; m < 4; m++)
#pragma unroll
        for (int j = 0; j < 4; j++) part[m][j] = 0.f;
#pragma unroll
    for (int m = 0; m < 4; m++)
#pragma unroll
        for (int n = 0; n < 4; n++)
#pragma unroll
            for (int j = 0; j < 4; j++) {
                int r = m * 16 + hi * 4 + j;
                int cc = w * 64 + n * 16 + lo;
                const char* p = xbB + r * 512 + ((cc * 2) ^ ((r & 7) << 4));
                float xf = (bf2f(*(const u16*)p) + ssilu(acc[m][n][j])) * INV_SQRT2;
                part[m][j] += xf * wo[n];
            }
#pragma unroll
    for (int m = 0; m < 4; m++)
#pragma unroll
        for (int j = 0; j < 4; j++) {
            float v = part[m][j];
            v += __shfl_xor(v, 1);
            v += __shfl_xor(v, 2);
            v += __shfl_xor(v, 4);
            v += __shfl_xor(v, 8);
            if (lo == 0) fpart[w][m * 16 + hi * 4 + j] = v;
        }
    __syncthreads();

    if (t < 64) {
        int r = t;
        float F = fpart[0][r] + fpart[1][r] + fpart[2][r] + fpart[3][r];
        long e = rowbase + r;
        float vx = evec[e * 3 + 0], vy = evec[e * 3 + 1], vz = evec[e * 3 + 2];
        int a = eidx[e];
        atomicAdd(&out[a * 3 + 0], F * vx);
        atomicAdd(&out[a * 3 + 1], F * vy);
        atomicAdd(&out[a * 3 + 2], F * vz);
    }
}

extern "C" void kernel_launch(void* const* d_in, const int* in_sizes, int n_in,
                              void* d_out, int out_size, void* d_ws, size_t ws_size,
                              hipStream_t stream) {
    const float* x_cat = (const float*)d_in[0];
    const float* evec  = (const float*)d_in[1];
    const int*   eidx  = (const int*)d_in[2];
    const float* Win   = (const float*)d_in[3];
    const float* W1a   = (const float*)d_in[4];
    const float* W1b   = (const float*)d_in[5];
    const float* W2a   = (const float*)d_in[6];
    const float* W2b   = (const float*)d_in[7];
    const float* Wout  = (const float*)d_in[8];
    float* out = (float*)d_out;
    const int E = in_sizes[1] / 3;   // 200000

    u16* WinF  = (u16*)d_ws;          // 327680 elems
    u16* Wfrag = WinF + 327680;       // 262144 elems

    int prepN = 327680 + 262144 + out_size;
    prep_kernel<<<(prepN + 255) / 256, 256, 0, stream>>>(
        Win, W1a, W1b, W2a, W2b, WinF, Wfrag, out, out_size);
    fused_kernel<<<E / 64, 256, 0, stream>>>(
        x_cat, WinF, Wfrag, Wout, evec, eidx, out);
}